// Round 4
// baseline (18029.678 us; speedup 1.0000x reference)
//
#include <hip/hip_runtime.h>
#include <hip/hip_bf16.h>

__device__ __forceinline__ float wsum64(float v) {
#pragma unroll
  for (int m = 32; m > 0; m >>= 1) v += __shfl_xor(v, m, 64);
  return v;
}
__device__ __forceinline__ float gsum16(float v) {
#pragma unroll
  for (int m = 8; m > 0; m >>= 1) v += __shfl_xor(v, m, 16);
  return v;
}
__device__ __forceinline__ float lrelu(float x) { return x > 0.f ? x : 0.2f * x; }
__device__ __forceinline__ float sigf(float x) { return 1.f / (1.f + __expf(-x)); }
__device__ __forceinline__ float bcast(float v, int srclane) {
  return __int_as_float(__builtin_amdgcn_readlane(__float_as_int(v), srclane));
}

// ---------------- CSR build ----------------
__global__ void hist_k(const int* __restrict__ dst, int* __restrict__ cnt, int e) {
  int i = blockIdx.x * blockDim.x + threadIdx.x;
  if (i < e) atomicAdd(&cnt[dst[i]], 1);
}

__global__ __launch_bounds__(256) void bsum_k(const int* __restrict__ cnt,
                                              int* __restrict__ bsum, int n) {
  __shared__ int red[4];
  int base = blockIdx.x * 1024;
  int t = threadIdx.x;
  int v = 0;
#pragma unroll
  for (int i = 0; i < 4; i++) {
    int idx = base + t + i * 256;
    v += (idx < n) ? cnt[idx] : 0;
  }
#pragma unroll
  for (int m = 32; m > 0; m >>= 1) v += __shfl_xor(v, m, 64);
  if ((t & 63) == 0) red[t >> 6] = v;
  __syncthreads();
  if (t == 0) bsum[blockIdx.x] = red[0] + red[1] + red[2] + red[3];
}

__global__ __launch_bounds__(1024) void scan_bsum_k(int* __restrict__ bsum,
                                                    int* __restrict__ rpn, int nb) {
  __shared__ int buf[1024];
  int t = threadIdx.x;
  int v = (t < nb) ? bsum[t] : 0;
  buf[t] = v;
  __syncthreads();
  int val = v;
  for (int off = 1; off < 1024; off <<= 1) {
    int u = (t >= off) ? buf[t - off] : 0;
    __syncthreads();
    val += u;
    buf[t] = val;
    __syncthreads();
  }
  if (t < nb) bsum[t] = val - v;
  if (t == nb - 1) *rpn = val;
}

__global__ __launch_bounds__(1024) void scan_fin_k(const int* __restrict__ cnt,
                                                   const int* __restrict__ bsum,
                                                   int* __restrict__ rp,
                                                   int* __restrict__ cursor, int n) {
  __shared__ int buf[1024];
  int t = threadIdx.x;
  int idx = blockIdx.x * 1024 + t;
  int v = (idx < n) ? cnt[idx] : 0;
  buf[t] = v;
  __syncthreads();
  int val = v;
  for (int off = 1; off < 1024; off <<= 1) {
    int u = (t >= off) ? buf[t - off] : 0;
    __syncthreads();
    val += u;
    buf[t] = val;
    __syncthreads();
  }
  if (idx < n) {
    int e = bsum[blockIdx.x] + val - v;
    rp[idx] = e;
    cursor[idx] = e;
  }
}

__global__ void scatter_k(const int* __restrict__ src, const int* __restrict__ dst,
                          int* __restrict__ cursor, int* __restrict__ srcs, int e) {
  int i = blockIdx.x * blockDim.x + threadIdx.x;
  if (i < e) {
    int pos = atomicAdd(&cursor[dst[i]], 1);
    srcs[pos] = src[i];
  }
}

// ---------------- fused dense r+z gates (reg-resident x, readlane broadcast) ----------------
template <int FA>
__global__ __launch_bounds__(512) void mm_rz_k(
    const float* __restrict__ xa, const float* __restrict__ xb,
    const float* __restrict__ Wg, const float* __restrict__ al, const float* __restrict__ ar,
    float* __restrict__ hbuf, float* __restrict__ elrz, float* __restrict__ errz, int n) {
  constexpr int KP = FA + 64;
  __shared__ float Wl[KP * 128];       // [k][gate][col], stride-1 cols -> conflict-free b32
  const float* Wr = Wg;
  const float* Wz = Wg + (size_t)KP * 64;
  for (int i = threadIdx.x; i < KP * 64; i += 512) {
    int k = i >> 6, c = i & 63;
    Wl[k * 128 + c] = Wr[i];
    Wl[k * 128 + 64 + c] = Wz[i];
  }
  __syncthreads();
  int lane = threadIdx.x & 63, w = threadIdx.x >> 6;
  int rb = __builtin_amdgcn_readfirstlane(blockIdx.x * 64 + w * 8);
  if (rb >= n) return;
  float alr = al[lane], arr_ = ar[lane];
  float alz = al[64 + lane], arz = ar[64 + lane];
  // lane l holds x[row][2l], x[row][2l+1] in registers (coalesced float2 loads)
  float xlo[8], xhi[8];
  int k0 = lane * 2;
#pragma unroll
  for (int i = 0; i < 8; i++) {
    int r = rb + i; if (r >= n) r = n - 1;
    float2 v = {0.f, 0.f};
    if (k0 < FA) v = *(const float2*)&xa[(size_t)r * FA + k0];
    else if (k0 < KP) v = *(const float2*)&xb[(size_t)r * 64 + (k0 - FA)];
    xlo[i] = v.x; xhi[i] = v.y;
  }
  float accr[8], accz[8];
#pragma unroll
  for (int i = 0; i < 8; i++) { accr[i] = 0.f; accz[i] = 0.f; }
#pragma unroll
  for (int k = 0; k < KP; k++) {
    float wr = Wl[k * 128 + lane];
    float wz = Wl[k * 128 + 64 + lane];
#pragma unroll
    for (int i = 0; i < 8; i++) {
      float xv = bcast((k & 1) ? xhi[i] : xlo[i], k >> 1);
      accr[i] = fmaf(xv, wr, accr[i]);
      accz[i] = fmaf(xv, wz, accz[i]);
    }
  }
#pragma unroll
  for (int i = 0; i < 8; i++) {
    int r = rb + i;
    bool ok = r < n;
    if (ok) {
      hbuf[(size_t)r * 128 + lane] = accr[i];
      hbuf[(size_t)r * 128 + 64 + lane] = accz[i];
    }
    float s0 = wsum64(accr[i] * alr);
    float s1 = wsum64(accz[i] * alz);
    float s2 = wsum64(accr[i] * arr_);
    float s3 = wsum64(accz[i] * arz);
    if (ok && lane == 0) {
      elrz[(size_t)r * 2 + 0] = s0;
      elrz[(size_t)r * 2 + 1] = s1;
      errz[(size_t)r * 2 + 0] = s2;
      errz[(size_t)r * 2 + 1] = s3;
    }
  }
}

// ---------------- dense candidate gate ----------------
template <int FA>
__global__ __launch_bounds__(512) void mm_c_k(
    const float* __restrict__ xa, const float* __restrict__ xb,
    const float* __restrict__ Wc, const float* __restrict__ al, const float* __restrict__ ar,
    float* __restrict__ hc, float* __restrict__ elc, float* __restrict__ erc, int n) {
  constexpr int KP = FA + 64;
  __shared__ float Wl[KP * 64];
  for (int i = threadIdx.x; i < KP * 64; i += 512) Wl[i] = Wc[i];
  __syncthreads();
  int lane = threadIdx.x & 63, w = threadIdx.x >> 6;
  int rb = __builtin_amdgcn_readfirstlane(blockIdx.x * 64 + w * 8);
  if (rb >= n) return;
  float alv = al[lane], arv = ar[lane];
  float xlo[8], xhi[8];
  int k0 = lane * 2;
#pragma unroll
  for (int i = 0; i < 8; i++) {
    int r = rb + i; if (r >= n) r = n - 1;
    float2 v = {0.f, 0.f};
    if (k0 < FA) v = *(const float2*)&xa[(size_t)r * FA + k0];
    else if (k0 < KP) v = *(const float2*)&xb[(size_t)r * 64 + (k0 - FA)];
    xlo[i] = v.x; xhi[i] = v.y;
  }
  float acc[8];
#pragma unroll
  for (int i = 0; i < 8; i++) acc[i] = 0.f;
#pragma unroll
  for (int k = 0; k < KP; k++) {
    float wv = Wl[k * 64 + lane];
#pragma unroll
    for (int i = 0; i < 8; i++) {
      float xv = bcast((k & 1) ? xhi[i] : xlo[i], k >> 1);
      acc[i] = fmaf(xv, wv, acc[i]);
    }
  }
#pragma unroll
  for (int i = 0; i < 8; i++) {
    int r = rb + i;
    bool ok = r < n;
    if (ok) hc[(size_t)r * 64 + lane] = acc[i];
    float s0 = wsum64(acc[i] * alv);
    float s1 = wsum64(acc[i] * arv);
    if (ok && lane == 0) { elc[r] = s0; erc[r] = s1; }
  }
}

// ---------------- edge softmax + aggregate r,z (fixed-trip unrolled gather) ----------------
__global__ __launch_bounds__(256) void agg_rz_k(
    const int* __restrict__ rp, const int* __restrict__ srcs,
    const float* __restrict__ hbuf, const float* __restrict__ elrz, const float* __restrict__ errz,
    const float* __restrict__ b,
    const float* __restrict__ hx, float* __restrict__ rh, float* __restrict__ zb, int n) {
  int l16 = threadIdx.x & 15;
  int d = (blockIdx.x * 256 + threadIdx.x) >> 4;
  if (d >= n) return;
  int beg = rp[d], deg = rp[d + 1] - beg;
  float2 erd = ((const float2*)errz)[d];
  const float4* h4 = (const float4*)hbuf;
  float4 accr = {0, 0, 0, 0}, accz = {0, 0, 0, 0};
  float sr = 0.f, sz = 0.f;
  for (int base = 0; base < deg; base += 16) {
    int k = base + l16;
    int s = 0;
    float exr = 0.f, exz = 0.f;
    if (k < deg) {
      s = srcs[beg + k];
      float2 el = ((const float2*)elrz)[s];
      exr = __expf(lrelu(el.x + erd.x));
      exz = __expf(lrelu(el.y + erd.y));
      sr += exr; sz += exz;
    }
#pragma unroll
    for (int j = 0; j < 16; j++) {
      int sj = __shfl(s, j, 16);
      float aj = __shfl(exr, j, 16);
      float zj = __shfl(exz, j, 16);
      float4 hr = h4[(size_t)sj * 32 + l16];
      float4 hz = h4[(size_t)sj * 32 + 16 + l16];
      accr.x = fmaf(aj, hr.x, accr.x); accr.y = fmaf(aj, hr.y, accr.y);
      accr.z = fmaf(aj, hr.z, accr.z); accr.w = fmaf(aj, hr.w, accr.w);
      accz.x = fmaf(zj, hz.x, accz.x); accz.y = fmaf(zj, hz.y, accz.y);
      accz.z = fmaf(zj, hz.z, accz.z); accz.w = fmaf(zj, hz.w, accz.w);
    }
  }
  sr = gsum16(sr); sz = gsum16(sz);
  float invr = 1.f / fmaxf(sr, 1e-9f);
  float invz = 1.f / fmaxf(sz, 1e-9f);
  float4 br4 = ((const float4*)b)[l16];
  float4 bz4 = ((const float4*)(b + 64))[l16];
  float4 hx4 = ((const float4*)hx)[(size_t)d * 16 + l16];
  float4 rv, zv;
  rv.x = sigf(fmaf(accr.x, invr, br4.x)) * hx4.x;
  rv.y = sigf(fmaf(accr.y, invr, br4.y)) * hx4.y;
  rv.z = sigf(fmaf(accr.z, invr, br4.z)) * hx4.z;
  rv.w = sigf(fmaf(accr.w, invr, br4.w)) * hx4.w;
  zv.x = sigf(fmaf(accz.x, invz, bz4.x));
  zv.y = sigf(fmaf(accz.y, invz, bz4.y));
  zv.z = sigf(fmaf(accz.z, invz, bz4.z));
  zv.w = sigf(fmaf(accz.w, invz, bz4.w));
  ((float4*)rh)[(size_t)d * 16 + l16] = rv;
  ((float4*)zb)[(size_t)d * 16 + l16] = zv;
}

// ---------------- candidate aggregate + state update (+ optional proj) ----------------
__global__ __launch_bounds__(256) void agg_c_k(
    const int* __restrict__ rp, const int* __restrict__ srcs,
    const float* __restrict__ hc, const float* __restrict__ elc, const float* __restrict__ erc,
    const float* __restrict__ b, const float* __restrict__ zb, float* __restrict__ hstate,
    const float* __restrict__ projW, const float* __restrict__ projb,
    float* __restrict__ outp, int n) {
  int l16 = threadIdx.x & 15;
  int d = (blockIdx.x * 256 + threadIdx.x) >> 4;
  if (d >= n) return;
  int beg = rp[d], deg = rp[d + 1] - beg;
  float erd = erc[d];
  const float4* h4 = (const float4*)hc;
  float4 acc = {0, 0, 0, 0};
  float ssum = 0.f;
  for (int base = 0; base < deg; base += 16) {
    int k = base + l16;
    int s = 0;
    float ex = 0.f;
    if (k < deg) {
      s = srcs[beg + k];
      ex = __expf(lrelu(elc[s] + erd));
      ssum += ex;
    }
#pragma unroll
    for (int j = 0; j < 16; j++) {
      int sj = __shfl(s, j, 16);
      float aj = __shfl(ex, j, 16);
      float4 hv = h4[(size_t)sj * 16 + l16];
      acc.x = fmaf(aj, hv.x, acc.x); acc.y = fmaf(aj, hv.y, acc.y);
      acc.z = fmaf(aj, hv.z, acc.z); acc.w = fmaf(aj, hv.w, acc.w);
    }
  }
  ssum = gsum16(ssum);
  float inv = 1.f / fmaxf(ssum, 1e-9f);
  float4 bc4 = ((const float4*)b)[l16];
  float4 z4 = ((const float4*)zb)[(size_t)d * 16 + l16];
  float4 hx4 = ((const float4*)hstate)[(size_t)d * 16 + l16];
  float4 hcv, hn;
  hcv.x = tanhf(fmaf(acc.x, inv, bc4.x));
  hcv.y = tanhf(fmaf(acc.y, inv, bc4.y));
  hcv.z = tanhf(fmaf(acc.z, inv, bc4.z));
  hcv.w = tanhf(fmaf(acc.w, inv, bc4.w));
  hn.x = z4.x * hx4.x + (1.f - z4.x) * hcv.x;
  hn.y = z4.y * hx4.y + (1.f - z4.y) * hcv.y;
  hn.z = z4.z * hx4.z + (1.f - z4.z) * hcv.z;
  hn.w = z4.w * hx4.w + (1.f - z4.w) * hcv.w;
  ((float4*)hstate)[(size_t)d * 16 + l16] = hn;
  if (outp) {
    const float4* wp4 = (const float4*)projW;   // [64][2] row-major
    float4 a0 = wp4[l16 * 2], a1 = wp4[l16 * 2 + 1];
    float p0 = hn.x * a0.x + hn.y * a0.z + hn.z * a1.x + hn.w * a1.z;
    float p1 = hn.x * a0.y + hn.y * a0.w + hn.z * a1.y + hn.w * a1.w;
    p0 = gsum16(p0); p1 = gsum16(p1);
    if (l16 == 0) {
      outp[(size_t)d * 2 + 0] = p0 + projb[0];
      outp[(size_t)d * 2 + 1] = p1 + projb[1];
    }
  }
}

extern "C" void kernel_launch(void* const* d_in, const int* in_sizes, int n_in,
                              void* d_out, int out_size, void* d_ws, size_t ws_size,
                              hipStream_t stream) {
  const int T = 12, HZN = 12, F = 2, H = 64;
  const float* x = (const float*)d_in[0];
  const int* src = (const int*)d_in[1];
  const int* dst = (const int*)d_in[2];
  const float* enc_W0 = (const float*)d_in[3];
  const float* enc_al0 = (const float*)d_in[4];
  const float* enc_ar0 = (const float*)d_in[5];
  const float* enc_b0 = (const float*)d_in[6];
  const float* enc_W1 = (const float*)d_in[7];
  const float* enc_al1 = (const float*)d_in[8];
  const float* enc_ar1 = (const float*)d_in[9];
  const float* enc_b1 = (const float*)d_in[10];
  const float* dec_W0 = (const float*)d_in[11];
  const float* dec_al0 = (const float*)d_in[12];
  const float* dec_ar0 = (const float*)d_in[13];
  const float* dec_b0 = (const float*)d_in[14];
  const float* dec_W1 = (const float*)d_in[15];
  const float* dec_al1 = (const float*)d_in[16];
  const float* dec_ar1 = (const float*)d_in[17];
  const float* dec_b1 = (const float*)d_in[18];
  const float* proj_W = (const float*)d_in[19];
  const float* proj_b = (const float*)d_in[20];
  float* out = (float*)d_out;

  const int E = in_sizes[1];
  const int N = in_sizes[0] / (T * F);
  const int NB = (N + 1023) / 1024;

  char* wp = (char*)d_ws;
  size_t off = 0;
  auto carve = [&](size_t bytes) {
    void* p = wp + off;
    off = (off + bytes + 255) & ~(size_t)255;
    return p;
  };
  int* counts = (int*)carve((size_t)N * 4);
  int* bsum = (int*)carve((size_t)NB * 4);
  int* rp = (int*)carve((size_t)(N + 1) * 4);
  int* cursor = (int*)carve((size_t)N * 4);
  int* srcs = (int*)carve((size_t)E * 4);
  float* hs0 = (float*)carve((size_t)N * H * 4);
  float* hs1 = (float*)carve((size_t)N * H * 4);
  float* hbuf = (float*)carve((size_t)N * 2 * H * 4);
  float* elrz = (float*)carve((size_t)N * 2 * 4);
  float* errz = (float*)carve((size_t)N * 2 * 4);
  float* hc = (float*)carve((size_t)N * H * 4);
  float* elc = (float*)carve((size_t)N * 4);
  float* erc = (float*)carve((size_t)N * 4);
  float* rh = (float*)carve((size_t)N * H * 4);
  float* zbuf = (float*)carve((size_t)N * H * 4);
  float* zero2 = (float*)carve((size_t)N * F * 4);
  (void)ws_size;

  const int G_E = (E + 255) / 256;
  const int G_MM = (N + 63) / 64;
  const int G_AG = (N + 15) / 16;

  // ---- CSR by destination ----
  hipMemsetAsync(counts, 0, (size_t)N * 4, stream);
  hist_k<<<G_E, 256, 0, stream>>>(dst, counts, E);
  bsum_k<<<NB, 256, 0, stream>>>(counts, bsum, N);
  scan_bsum_k<<<1, 1024, 0, stream>>>(bsum, rp + N, NB);
  scan_fin_k<<<NB, 1024, 0, stream>>>(counts, bsum, rp, cursor, N);
  scatter_k<<<G_E, 256, 0, stream>>>(src, dst, cursor, srcs, E);

  // ---- init states ----
  hipMemsetAsync(hs0, 0, (size_t)N * H * 4, stream);
  hipMemsetAsync(hs1, 0, (size_t)N * H * 4, stream);
  hipMemsetAsync(zero2, 0, (size_t)N * F * 4, stream);

  auto run_gru = [&](const float* xa, int FA, float* hstate,
                     const float* W, const float* al, const float* ar, const float* b,
                     float* outp) {
    int fin = FA + H;
    if (FA == 2) {
      mm_rz_k<2><<<G_MM, 512, 0, stream>>>(xa, hstate, W, al, ar, hbuf, elrz, errz, N);
    } else {
      mm_rz_k<64><<<G_MM, 512, 0, stream>>>(xa, hstate, W, al, ar, hbuf, elrz, errz, N);
    }
    agg_rz_k<<<G_AG, 256, 0, stream>>>(rp, srcs, hbuf, elrz, errz, b, hstate, rh, zbuf, N);
    if (FA == 2) {
      mm_c_k<2><<<G_MM, 512, 0, stream>>>(xa, rh, W + (size_t)2 * fin * H, al + 128, ar + 128,
                                          hc, elc, erc, N);
    } else {
      mm_c_k<64><<<G_MM, 512, 0, stream>>>(xa, rh, W + (size_t)2 * fin * H, al + 128, ar + 128,
                                           hc, elc, erc, N);
    }
    agg_c_k<<<G_AG, 256, 0, stream>>>(rp, srcs, hc, elc, erc, b + 128, zbuf, hstate,
                                      proj_W, proj_b, outp, N);
  };

  // ---- encoder ----
  for (int t = 0; t < T; t++) {
    const float* xt = x + (size_t)t * N * F;
    run_gru(xt, 2, hs0, enc_W0, enc_al0, enc_ar0, enc_b0, nullptr);
    run_gru(hs0, 64, hs1, enc_W1, enc_al1, enc_ar1, enc_b1, nullptr);
  }

  // ---- decoder ----
  for (int t = 0; t < HZN; t++) {
    const float* xin = (t == 0) ? zero2 : (out + (size_t)(t - 1) * N * 2);
    run_gru(xin, 2, hs0, dec_W0, dec_al0, dec_ar0, dec_b0, nullptr);
    run_gru(hs0, 64, hs1, dec_W1, dec_al1, dec_ar1, dec_b1, out + (size_t)t * N * 2);
  }
  (void)out_size; (void)n_in;
}

// Round 5
// 8195.873 us; speedup vs baseline: 2.1998x; 2.1998x over previous
//
#include <hip/hip_runtime.h>
#include <hip/hip_bf16.h>

__device__ __forceinline__ float wsum64(float v) {
#pragma unroll
  for (int m = 32; m > 0; m >>= 1) v += __shfl_xor(v, m, 64);
  return v;
}
__device__ __forceinline__ float gsum16(float v) {
#pragma unroll
  for (int m = 8; m > 0; m >>= 1) v += __shfl_xor(v, m, 16);
  return v;
}
__device__ __forceinline__ float lrelu(float x) { return x > 0.f ? x : 0.2f * x; }
__device__ __forceinline__ float sigf(float x) { return 1.f / (1.f + __expf(-x)); }

// ---------------- CSR build ----------------
__global__ void hist_k(const int* __restrict__ dst, int* __restrict__ cnt, int e) {
  int i = blockIdx.x * blockDim.x + threadIdx.x;
  if (i < e) atomicAdd(&cnt[dst[i]], 1);
}

__global__ __launch_bounds__(256) void bsum_k(const int* __restrict__ cnt,
                                              int* __restrict__ bsum, int n) {
  __shared__ int red[4];
  int base = blockIdx.x * 1024;
  int t = threadIdx.x;
  int v = 0;
#pragma unroll
  for (int i = 0; i < 4; i++) {
    int idx = base + t + i * 256;
    v += (idx < n) ? cnt[idx] : 0;
  }
#pragma unroll
  for (int m = 32; m > 0; m >>= 1) v += __shfl_xor(v, m, 64);
  if ((t & 63) == 0) red[t >> 6] = v;
  __syncthreads();
  if (t == 0) bsum[blockIdx.x] = red[0] + red[1] + red[2] + red[3];
}

__global__ __launch_bounds__(1024) void scan_bsum_k(int* __restrict__ bsum,
                                                    int* __restrict__ rpn, int nb) {
  __shared__ int buf[1024];
  int t = threadIdx.x;
  int v = (t < nb) ? bsum[t] : 0;
  buf[t] = v;
  __syncthreads();
  int val = v;
  for (int off = 1; off < 1024; off <<= 1) {
    int u = (t >= off) ? buf[t - off] : 0;
    __syncthreads();
    val += u;
    buf[t] = val;
    __syncthreads();
  }
  if (t < nb) bsum[t] = val - v;
  if (t == nb - 1) *rpn = val;
}

__global__ __launch_bounds__(1024) void scan_fin_k(const int* __restrict__ cnt,
                                                   const int* __restrict__ bsum,
                                                   int* __restrict__ rp,
                                                   int* __restrict__ cursor, int n) {
  __shared__ int buf[1024];
  int t = threadIdx.x;
  int idx = blockIdx.x * 1024 + t;
  int v = (idx < n) ? cnt[idx] : 0;
  buf[t] = v;
  __syncthreads();
  int val = v;
  for (int off = 1; off < 1024; off <<= 1) {
    int u = (t >= off) ? buf[t - off] : 0;
    __syncthreads();
    val += u;
    buf[t] = val;
    __syncthreads();
  }
  if (idx < n) {
    int e = bsum[blockIdx.x] + val - v;
    rp[idx] = e;
    cursor[idx] = e;
  }
}

__global__ void scatter_k(const int* __restrict__ src, const int* __restrict__ dst,
                          int* __restrict__ cursor, int* __restrict__ srcs, int e) {
  int i = blockIdx.x * blockDim.x + threadIdx.x;
  if (i < e) {
    int pos = atomicAdd(&cursor[dst[i]], 1);
    srcs[pos] = src[i];
  }
}

// ---------------- dense gates: LDS-staged x + W, VALU streaming ----------------
// NG=2: gates r,z fused (W at Wg, Wg+KP*64). NG=1: candidate gate.
// Block: 512 thr = 8 waves; 4 rows/wave = 32 rows/block.
template <int FA, int NG>
__global__ __launch_bounds__(512) void mm_k(
    const float* __restrict__ xa, const float* __restrict__ xb,
    const float* __restrict__ Wg,
    const float* __restrict__ al, const float* __restrict__ ar,  // NG vectors of 64
    float* __restrict__ hb, float* __restrict__ el, float* __restrict__ er, int n) {
  constexpr int KP = FA + 64;
  __shared__ float Wl[KP * 64 * NG];   // NG=2: [k*64+c][g] interleaved; NG=1: [k*64+c]
  __shared__ float Xl[32 * KP];        // [row][k]
  // stage W (coalesced global, once per block)
  for (int i = threadIdx.x; i < KP * 64; i += 512) {
    if (NG == 2) {
      float2 wv = {Wg[i], Wg[(size_t)KP * 64 + i]};
      *(float2*)&Wl[i * 2] = wv;
    } else {
      Wl[i] = Wg[i];
    }
  }
  // stage x tile (coalesced vector-lane loads)
  int rbase = blockIdx.x * 32;
  for (int i = threadIdx.x; i < 32 * KP; i += 512) {
    int row = i / KP, k = i - row * KP;
    int r = rbase + row; if (r >= n) r = n - 1;
    Xl[i] = (k < FA) ? xa[(size_t)r * FA + k] : xb[(size_t)r * 64 + (k - FA)];
  }
  __syncthreads();
  int lane = threadIdx.x & 63, w = threadIdx.x >> 6;
  int rb = rbase + w * 4;
  if (rb >= n) return;
  float a_l[NG], a_r[NG];
#pragma unroll
  for (int g = 0; g < NG; g++) { a_l[g] = al[g * 64 + lane]; a_r[g] = ar[g * 64 + lane]; }
  float acc[4][NG];
#pragma unroll
  for (int i = 0; i < 4; i++)
#pragma unroll
    for (int g = 0; g < NG; g++) acc[i][g] = 0.f;
  const int xoff = (w * 4) * KP;
#pragma unroll 8
  for (int k = 0; k < KP; k += 2) {
    float2 w0, w1;
    if (NG == 2) {
      w0 = *(const float2*)&Wl[(k * 64 + lane) * 2];
      w1 = *(const float2*)&Wl[((k + 1) * 64 + lane) * 2];
    } else {
      w0.x = Wl[k * 64 + lane]; w0.y = 0.f;
      w1.x = Wl[(k + 1) * 64 + lane]; w1.y = 0.f;
    }
#pragma unroll
    for (int i = 0; i < 4; i++) {
      float2 xv = *(const float2*)&Xl[xoff + i * KP + k];   // broadcast read
      acc[i][0] = fmaf(xv.x, w0.x, acc[i][0]);
      acc[i][0] = fmaf(xv.y, w1.x, acc[i][0]);
      if (NG == 2) {
        acc[i][1] = fmaf(xv.x, w0.y, acc[i][1]);
        acc[i][1] = fmaf(xv.y, w1.y, acc[i][1]);
      }
    }
  }
#pragma unroll
  for (int i = 0; i < 4; i++) {
    int r = rb + i;
    bool ok = r < n;
#pragma unroll
    for (int g = 0; g < NG; g++) {
      if (ok) hb[(size_t)r * (64 * NG) + g * 64 + lane] = acc[i][g];
      float sl = wsum64(acc[i][g] * a_l[g]);
      float sr = wsum64(acc[i][g] * a_r[g]);
      if (ok && lane == 0) {
        el[(size_t)r * NG + g] = sl;
        er[(size_t)r * NG + g] = sr;
      }
    }
  }
}

// ---------------- edge softmax + aggregate r,z (fixed-trip unrolled gather) ----------------
__global__ __launch_bounds__(256) void agg_rz_k(
    const int* __restrict__ rp, const int* __restrict__ srcs,
    const float* __restrict__ hbuf, const float* __restrict__ elrz, const float* __restrict__ errz,
    const float* __restrict__ b,
    const float* __restrict__ hx, float* __restrict__ rh, float* __restrict__ zb, int n) {
  int l16 = threadIdx.x & 15;
  int d = (blockIdx.x * 256 + threadIdx.x) >> 4;
  if (d >= n) return;
  int beg = rp[d], deg = rp[d + 1] - beg;
  float2 erd = ((const float2*)errz)[d];
  const float4* h4 = (const float4*)hbuf;
  float4 accr = {0, 0, 0, 0}, accz = {0, 0, 0, 0};
  float sr = 0.f, sz = 0.f;
  for (int base = 0; base < deg; base += 16) {
    int k = base + l16;
    int s = 0;
    float exr = 0.f, exz = 0.f;
    if (k < deg) {
      s = srcs[beg + k];
      float2 el = ((const float2*)elrz)[s];
      exr = __expf(lrelu(el.x + erd.x));
      exz = __expf(lrelu(el.y + erd.y));
      sr += exr; sz += exz;
    }
#pragma unroll
    for (int j = 0; j < 16; j++) {
      int sj = __shfl(s, j, 16);
      float aj = __shfl(exr, j, 16);
      float zj = __shfl(exz, j, 16);
      float4 hr = h4[(size_t)sj * 32 + l16];
      float4 hz = h4[(size_t)sj * 32 + 16 + l16];
      accr.x = fmaf(aj, hr.x, accr.x); accr.y = fmaf(aj, hr.y, accr.y);
      accr.z = fmaf(aj, hr.z, accr.z); accr.w = fmaf(aj, hr.w, accr.w);
      accz.x = fmaf(zj, hz.x, accz.x); accz.y = fmaf(zj, hz.y, accz.y);
      accz.z = fmaf(zj, hz.z, accz.z); accz.w = fmaf(zj, hz.w, accz.w);
    }
  }
  sr = gsum16(sr); sz = gsum16(sz);
  float invr = 1.f / fmaxf(sr, 1e-9f);
  float invz = 1.f / fmaxf(sz, 1e-9f);
  float4 br4 = ((const float4*)b)[l16];
  float4 bz4 = ((const float4*)(b + 64))[l16];
  float4 hx4 = ((const float4*)hx)[(size_t)d * 16 + l16];
  float4 rv, zv;
  rv.x = sigf(fmaf(accr.x, invr, br4.x)) * hx4.x;
  rv.y = sigf(fmaf(accr.y, invr, br4.y)) * hx4.y;
  rv.z = sigf(fmaf(accr.z, invr, br4.z)) * hx4.z;
  rv.w = sigf(fmaf(accr.w, invr, br4.w)) * hx4.w;
  zv.x = sigf(fmaf(accz.x, invz, bz4.x));
  zv.y = sigf(fmaf(accz.y, invz, bz4.y));
  zv.z = sigf(fmaf(accz.z, invz, bz4.z));
  zv.w = sigf(fmaf(accz.w, invz, bz4.w));
  ((float4*)rh)[(size_t)d * 16 + l16] = rv;
  ((float4*)zb)[(size_t)d * 16 + l16] = zv;
}

// ---------------- candidate aggregate + state update (+ optional proj) ----------------
__global__ __launch_bounds__(256) void agg_c_k(
    const int* __restrict__ rp, const int* __restrict__ srcs,
    const float* __restrict__ hc, const float* __restrict__ elc, const float* __restrict__ erc,
    const float* __restrict__ b, const float* __restrict__ zb, float* __restrict__ hstate,
    const float* __restrict__ projW, const float* __restrict__ projb,
    float* __restrict__ outp, int n) {
  int l16 = threadIdx.x & 15;
  int d = (blockIdx.x * 256 + threadIdx.x) >> 4;
  if (d >= n) return;
  int beg = rp[d], deg = rp[d + 1] - beg;
  float erd = erc[d];
  const float4* h4 = (const float4*)hc;
  float4 acc = {0, 0, 0, 0};
  float ssum = 0.f;
  for (int base = 0; base < deg; base += 16) {
    int k = base + l16;
    int s = 0;
    float ex = 0.f;
    if (k < deg) {
      s = srcs[beg + k];
      ex = __expf(lrelu(elc[s] + erd));
      ssum += ex;
    }
#pragma unroll
    for (int j = 0; j < 16; j++) {
      int sj = __shfl(s, j, 16);
      float aj = __shfl(ex, j, 16);
      float4 hv = h4[(size_t)sj * 16 + l16];
      acc.x = fmaf(aj, hv.x, acc.x); acc.y = fmaf(aj, hv.y, acc.y);
      acc.z = fmaf(aj, hv.z, acc.z); acc.w = fmaf(aj, hv.w, acc.w);
    }
  }
  ssum = gsum16(ssum);
  float inv = 1.f / fmaxf(ssum, 1e-9f);
  float4 bc4 = ((const float4*)b)[l16];
  float4 z4 = ((const float4*)zb)[(size_t)d * 16 + l16];
  float4 hx4 = ((const float4*)hstate)[(size_t)d * 16 + l16];
  float4 hcv, hn;
  hcv.x = tanhf(fmaf(acc.x, inv, bc4.x));
  hcv.y = tanhf(fmaf(acc.y, inv, bc4.y));
  hcv.z = tanhf(fmaf(acc.z, inv, bc4.z));
  hcv.w = tanhf(fmaf(acc.w, inv, bc4.w));
  hn.x = z4.x * hx4.x + (1.f - z4.x) * hcv.x;
  hn.y = z4.y * hx4.y + (1.f - z4.y) * hcv.y;
  hn.z = z4.z * hx4.z + (1.f - z4.z) * hcv.z;
  hn.w = z4.w * hx4.w + (1.f - z4.w) * hcv.w;
  ((float4*)hstate)[(size_t)d * 16 + l16] = hn;
  if (outp) {
    const float4* wp4 = (const float4*)projW;   // [64][2] row-major
    float4 a0 = wp4[l16 * 2], a1 = wp4[l16 * 2 + 1];
    float p0 = hn.x * a0.x + hn.y * a0.z + hn.z * a1.x + hn.w * a1.z;
    float p1 = hn.x * a0.y + hn.y * a0.w + hn.z * a1.y + hn.w * a1.w;
    p0 = gsum16(p0); p1 = gsum16(p1);
    if (l16 == 0) {
      outp[(size_t)d * 2 + 0] = p0 + projb[0];
      outp[(size_t)d * 2 + 1] = p1 + projb[1];
    }
  }
}

extern "C" void kernel_launch(void* const* d_in, const int* in_sizes, int n_in,
                              void* d_out, int out_size, void* d_ws, size_t ws_size,
                              hipStream_t stream) {
  const int T = 12, HZN = 12, F = 2, H = 64;
  const float* x = (const float*)d_in[0];
  const int* src = (const int*)d_in[1];
  const int* dst = (const int*)d_in[2];
  const float* enc_W0 = (const float*)d_in[3];
  const float* enc_al0 = (const float*)d_in[4];
  const float* enc_ar0 = (const float*)d_in[5];
  const float* enc_b0 = (const float*)d_in[6];
  const float* enc_W1 = (const float*)d_in[7];
  const float* enc_al1 = (const float*)d_in[8];
  const float* enc_ar1 = (const float*)d_in[9];
  const float* enc_b1 = (const float*)d_in[10];
  const float* dec_W0 = (const float*)d_in[11];
  const float* dec_al0 = (const float*)d_in[12];
  const float* dec_ar0 = (const float*)d_in[13];
  const float* dec_b0 = (const float*)d_in[14];
  const float* dec_W1 = (const float*)d_in[15];
  const float* dec_al1 = (const float*)d_in[16];
  const float* dec_ar1 = (const float*)d_in[17];
  const float* dec_b1 = (const float*)d_in[18];
  const float* proj_W = (const float*)d_in[19];
  const float* proj_b = (const float*)d_in[20];
  float* out = (float*)d_out;

  const int E = in_sizes[1];
  const int N = in_sizes[0] / (T * F);
  const int NB = (N + 1023) / 1024;

  char* wp = (char*)d_ws;
  size_t off = 0;
  auto carve = [&](size_t bytes) {
    void* p = wp + off;
    off = (off + bytes + 255) & ~(size_t)255;
    return p;
  };
  int* counts = (int*)carve((size_t)N * 4);
  int* bsum = (int*)carve((size_t)NB * 4);
  int* rp = (int*)carve((size_t)(N + 1) * 4);
  int* cursor = (int*)carve((size_t)N * 4);
  int* srcs = (int*)carve((size_t)E * 4);
  float* hs0 = (float*)carve((size_t)N * H * 4);
  float* hs1 = (float*)carve((size_t)N * H * 4);
  float* hbuf = (float*)carve((size_t)N * 2 * H * 4);
  float* elrz = (float*)carve((size_t)N * 2 * 4);
  float* errz = (float*)carve((size_t)N * 2 * 4);
  float* hc = (float*)carve((size_t)N * H * 4);
  float* elc = (float*)carve((size_t)N * 4);
  float* erc = (float*)carve((size_t)N * 4);
  float* rh = (float*)carve((size_t)N * H * 4);
  float* zbuf = (float*)carve((size_t)N * H * 4);
  float* zero2 = (float*)carve((size_t)N * F * 4);
  (void)ws_size;

  const int G_E = (E + 255) / 256;
  const int G_MM = (N + 31) / 32;   // 512 thr: 8 waves * 4 rows
  const int G_AG = (N + 15) / 16;

  // ---- CSR by destination ----
  hipMemsetAsync(counts, 0, (size_t)N * 4, stream);
  hist_k<<<G_E, 256, 0, stream>>>(dst, counts, E);
  bsum_k<<<NB, 256, 0, stream>>>(counts, bsum, N);
  scan_bsum_k<<<1, 1024, 0, stream>>>(bsum, rp + N, NB);
  scan_fin_k<<<NB, 1024, 0, stream>>>(counts, bsum, rp, cursor, N);
  scatter_k<<<G_E, 256, 0, stream>>>(src, dst, cursor, srcs, E);

  // ---- init states ----
  hipMemsetAsync(hs0, 0, (size_t)N * H * 4, stream);
  hipMemsetAsync(hs1, 0, (size_t)N * H * 4, stream);
  hipMemsetAsync(zero2, 0, (size_t)N * F * 4, stream);

  auto run_gru = [&](const float* xa, int FA, float* hstate,
                     const float* W, const float* al, const float* ar, const float* b,
                     float* outp) {
    int fin = FA + H;
    if (FA == 2) {
      mm_k<2, 2><<<G_MM, 512, 0, stream>>>(xa, hstate, W, al, ar, hbuf, elrz, errz, N);
    } else {
      mm_k<64, 2><<<G_MM, 512, 0, stream>>>(xa, hstate, W, al, ar, hbuf, elrz, errz, N);
    }
    agg_rz_k<<<G_AG, 256, 0, stream>>>(rp, srcs, hbuf, elrz, errz, b, hstate, rh, zbuf, N);
    if (FA == 2) {
      mm_k<2, 1><<<G_MM, 512, 0, stream>>>(xa, rh, W + (size_t)2 * fin * H, al + 128, ar + 128,
                                           hc, elc, erc, N);
    } else {
      mm_k<64, 1><<<G_MM, 512, 0, stream>>>(xa, rh, W + (size_t)2 * fin * H, al + 128, ar + 128,
                                            hc, elc, erc, N);
    }
    agg_c_k<<<G_AG, 256, 0, stream>>>(rp, srcs, hc, elc, erc, b + 128, zbuf, hstate,
                                      proj_W, proj_b, outp, N);
  };

  // ---- encoder ----
  for (int t = 0; t < T; t++) {
    const float* xt = x + (size_t)t * N * F;
    run_gru(xt, 2, hs0, enc_W0, enc_al0, enc_ar0, enc_b0, nullptr);
    run_gru(hs0, 64, hs1, enc_W1, enc_al1, enc_ar1, enc_b1, nullptr);
  }

  // ---- decoder ----
  for (int t = 0; t < HZN; t++) {
    const float* xin = (t == 0) ? zero2 : (out + (size_t)(t - 1) * N * 2);
    run_gru(xin, 2, hs0, dec_W0, dec_al0, dec_ar0, dec_b0, nullptr);
    run_gru(hs0, 64, hs1, dec_W1, dec_al1, dec_ar1, dec_b1, out + (size_t)t * N * 2);
  }
  (void)out_size; (void)n_in;
}